// Round 1
// baseline (40.711 us; speedup 1.0000x reference)
//
#include <hip/hip_runtime.h>

#define TV    512
#define TL    64
#define D_    512
#define BKT   64      // K tile
#define VROWS 128     // v rows per block
#define NCHUNK (TV/VROWS) // 4

typedef __attribute__((ext_vector_type(8))) short bf16x8;
typedef __attribute__((ext_vector_type(4))) float f32x4;

__device__ __forceinline__ short f2bf(float x){
  unsigned u = __float_as_uint(x);
  u += 0x7fffu + ((u >> 16) & 1u);   // round-to-nearest-even
  return (short)(u >> 16);
}

__global__ __launch_bounds__(256) void chamfer_main(
    const float* __restrict__ vf, const float* __restrict__ lf,
    const float* __restrict__ mv, const float* __restrict__ ml,
    float* __restrict__ pcol, float* __restrict__ psum)
{
  const int chunk = blockIdx.x;
  const int b     = blockIdx.y;
  const int t     = threadIdx.x;
  const int w     = t >> 6;
  const int lane  = t & 63;
  const int g     = lane >> 4;
  const int c15   = lane & 15;

  __shared__ __align__(16) short lv[VROWS * BKT];  // swizzled bf16 V-tile
  __shared__ __align__(16) short ll[TL * BKT];     // swizzled bf16 L-tile
  __shared__ float normv_s[VROWS];
  __shared__ float norml_s[TL];
  __shared__ float mvs[VROWS];
  __shared__ float mls[TL];
  __shared__ float wavecol[4][TL];
  __shared__ float wavesum[4];

  const int v0 = chunk * VROWS;
  const float* vbase = vf + ((size_t)b * TV + v0) * D_;
  const float* lbase = lf + (size_t)b * TL * D_;

  // stage masks once
  if (t < VROWS)                mvs[t]        = mv[(size_t)b * TV + v0 + t];
  else if (t < VROWS + TL)      mls[t - VROWS] = ml[(size_t)b * TL + (t - VROWS)];

  f32x4 acc[2][4];
  #pragma unroll
  for (int m = 0; m < 2; m++)
    #pragma unroll
    for (int n = 0; n < 4; n++)
      acc[m][n] = (f32x4){0.f, 0.f, 0.f, 0.f};

  float nvacc[4] = {0.f, 0.f, 0.f, 0.f};
  float nlacc[2] = {0.f, 0.f};

  for (int kt = 0; kt < D_ / BKT; ++kt) {
    // ---- stage V tile: 128 rows x 64 k (bf16, swizzled) ----
    #pragma unroll
    for (int p = 0; p < 4; p++) {
      int idx = p * 256 + t;
      int row = idx >> 3, kc = idx & 7;
      const float4* src = (const float4*)(vbase + (size_t)row * D_ + kt * BKT + kc * 8);
      float4 x0 = src[0], x1 = src[1];
      nvacc[p] += x0.x*x0.x + x0.y*x0.y + x0.z*x0.z + x0.w*x0.w
                + x1.x*x1.x + x1.y*x1.y + x1.z*x1.z + x1.w*x1.w;
      bf16x8 pk;
      pk[0]=f2bf(x0.x); pk[1]=f2bf(x0.y); pk[2]=f2bf(x0.z); pk[3]=f2bf(x0.w);
      pk[4]=f2bf(x1.x); pk[5]=f2bf(x1.y); pk[6]=f2bf(x1.z); pk[7]=f2bf(x1.w);
      int off = (row * 128 + kc * 16) ^ ((row & 7) << 4);
      *(bf16x8*)((char*)lv + off) = pk;
    }
    // ---- stage L tile: 64 rows x 64 k ----
    #pragma unroll
    for (int p = 0; p < 2; p++) {
      int idx = p * 256 + t;
      int row = idx >> 3, kc = idx & 7;
      const float4* src = (const float4*)(lbase + (size_t)row * D_ + kt * BKT + kc * 8);
      float4 x0 = src[0], x1 = src[1];
      nlacc[p] += x0.x*x0.x + x0.y*x0.y + x0.z*x0.z + x0.w*x0.w
                + x1.x*x1.x + x1.y*x1.y + x1.z*x1.z + x1.w*x1.w;
      bf16x8 pk;
      pk[0]=f2bf(x0.x); pk[1]=f2bf(x0.y); pk[2]=f2bf(x0.z); pk[3]=f2bf(x0.w);
      pk[4]=f2bf(x1.x); pk[5]=f2bf(x1.y); pk[6]=f2bf(x1.z); pk[7]=f2bf(x1.w);
      int off = (row * 128 + kc * 16) ^ ((row & 7) << 4);
      *(bf16x8*)((char*)ll + off) = pk;
    }
    __syncthreads();
    // ---- MFMA: 2 k-steps of 32 ----
    #pragma unroll
    for (int ks = 0; ks < 2; ks++) {
      bf16x8 afr[2], bfr[4];
      #pragma unroll
      for (int m = 0; m < 2; m++) {
        int row = w * 32 + m * 16 + c15;
        int off = (row * 128 + ks * 64 + g * 16) ^ ((row & 7) << 4);
        afr[m] = *(const bf16x8*)((const char*)lv + off);
      }
      #pragma unroll
      for (int n = 0; n < 4; n++) {
        int row = n * 16 + c15;
        int off = (row * 128 + ks * 64 + g * 16) ^ ((row & 7) << 4);
        bfr[n] = *(const bf16x8*)((const char*)ll + off);
      }
      #pragma unroll
      for (int m = 0; m < 2; m++)
        #pragma unroll
        for (int n = 0; n < 4; n++)
          acc[m][n] = __builtin_amdgcn_mfma_f32_16x16x32_bf16(afr[m], bfr[n], acc[m][n], 0, 0, 0);
    }
    __syncthreads();
  }

  // ---- row-norm reductions (8 consecutive lanes share a row) ----
  #pragma unroll
  for (int p = 0; p < 4; p++) {
    float s = nvacc[p];
    s += __shfl_xor(s, 1); s += __shfl_xor(s, 2); s += __shfl_xor(s, 4);
    if ((t & 7) == 0) normv_s[p * 32 + (t >> 3)] = s;
  }
  #pragma unroll
  for (int p = 0; p < 2; p++) {
    float s = nlacc[p];
    s += __shfl_xor(s, 1); s += __shfl_xor(s, 2); s += __shfl_xor(s, 4);
    if ((t & 7) == 0) norml_s[p * 32 + (t >> 3)] = s;
  }
  __syncthreads();

  // ---- epilogue: pd + masking, row/col mins ----
  const float BIG = 3.0e38f;
  float pdv[2][4][4];
  #pragma unroll
  for (int m = 0; m < 2; m++)
    #pragma unroll
    for (int n = 0; n < 4; n++)
      #pragma unroll
      for (int j = 0; j < 4; j++) {
        int row = w * 32 + m * 16 + g * 4 + j;
        int col = n * 16 + c15;
        float pd = normv_s[row] + norml_s[col] - 2.0f * acc[m][n][j];
        bool valid = (mvs[row] != 0.f) && (mls[col] != 0.f);
        pdv[m][n][j] = valid ? pd : BIG;
      }

  // row mins (over all 64 cols) -> masked sum over rows
  float svl = 0.f;
  #pragma unroll
  for (int m = 0; m < 2; m++)
    #pragma unroll
    for (int j = 0; j < 4; j++) {
      float rm = fminf(fminf(pdv[m][0][j], pdv[m][1][j]),
                       fminf(pdv[m][2][j], pdv[m][3][j]));
      rm = fminf(rm, __shfl_xor(rm, 1));
      rm = fminf(rm, __shfl_xor(rm, 2));
      rm = fminf(rm, __shfl_xor(rm, 4));
      rm = fminf(rm, __shfl_xor(rm, 8));
      int row = w * 32 + m * 16 + g * 4 + j;
      if (c15 == 0 && mvs[row] != 0.f) svl += rm;
    }
  svl += __shfl_xor(svl, 16);
  svl += __shfl_xor(svl, 32);
  if (lane == 0) wavesum[w] = svl;

  // col mins (over this wave's 32 rows)
  #pragma unroll
  for (int n = 0; n < 4; n++) {
    float cm = pdv[0][n][0];
    #pragma unroll
    for (int m = 0; m < 2; m++)
      #pragma unroll
      for (int j = 0; j < 4; j++)
        cm = fminf(cm, pdv[m][n][j]);
    cm = fminf(cm, __shfl_xor(cm, 16));
    cm = fminf(cm, __shfl_xor(cm, 32));
    if (g == 0) wavecol[w][n * 16 + c15] = cm;
  }
  __syncthreads();

  if (t < TL) {
    float cm = fminf(fminf(wavecol[0][t], wavecol[1][t]),
                     fminf(wavecol[2][t], wavecol[3][t]));
    pcol[((size_t)b * NCHUNK + chunk) * TL + t] = cm;
  }
  if (t == 0)
    psum[(size_t)b * NCHUNK + chunk] = wavesum[0] + wavesum[1] + wavesum[2] + wavesum[3];
}

__global__ __launch_bounds__(64) void chamfer_fin(
    const float* __restrict__ pcol, const float* __restrict__ psum,
    const float* __restrict__ mv, const float* __restrict__ ml,
    float* __restrict__ out)
{
  int b = blockIdx.x;
  int l = threadIdx.x;
  float cm = pcol[((size_t)b * 4 + 0) * 64 + l];
  cm = fminf(cm, pcol[((size_t)b * 4 + 1) * 64 + l]);
  cm = fminf(cm, pcol[((size_t)b * 4 + 2) * 64 + l]);
  cm = fminf(cm, pcol[((size_t)b * 4 + 3) * 64 + l]);
  float mlv = ml[(size_t)b * 64 + l];
  float sl = (mlv != 0.f) ? cm : 0.f;
  float nl = mlv;
  float nv = 0.f;
  #pragma unroll
  for (int i = 0; i < 8; i++) nv += mv[(size_t)b * 512 + l * 8 + i];
  float sv = (l < 4) ? psum[(size_t)b * 4 + l] : 0.f;
  #pragma unroll
  for (int s = 1; s < 64; s <<= 1) {
    sl += __shfl_xor(sl, s);
    nl += __shfl_xor(nl, s);
    nv += __shfl_xor(nv, s);
    sv += __shfl_xor(sv, s);
  }
  if (l == 0) out[b] = sl / nl + sv / nv;
}

extern "C" void kernel_launch(void* const* d_in, const int* in_sizes, int n_in,
                              void* d_out, int out_size, void* d_ws, size_t ws_size,
                              hipStream_t stream) {
  const float* vf = (const float*)d_in[0];
  const float* lf = (const float*)d_in[1];
  const float* mv = (const float*)d_in[2];
  const float* ml = (const float*)d_in[3];
  float* out  = (float*)d_out;
  float* pcol = (float*)d_ws;                  // [128][4][64]
  float* psum = pcol + 128 * 4 * 64;           // [128][4]
  dim3 grid(NCHUNK, 128);
  chamfer_main<<<grid, 256, 0, stream>>>(vf, lf, mv, ml, pcol, psum);
  chamfer_fin<<<128, 64, 0, stream>>>(pcol, psum, mv, ml, out);
}